// Round 11
// baseline (128.816 us; speedup 1.0000x reference)
//
#include <hip/hip_runtime.h>

#define B_N 4096
#define F_N 1024
#define H_N 4
#define D_N 256
#define BF_ELEMS (B_N * F_N)   // 4194304

typedef unsigned short u16;
typedef __bf16 bf16x8 __attribute__((ext_vector_type(8)));
typedef float f32x4 __attribute__((ext_vector_type(4)));
typedef u16 u16x4 __attribute__((ext_vector_type(4)));
typedef u16 u16x8 __attribute__((ext_vector_type(8)));

__device__ __forceinline__ u16 f2bf(float v) {
    union { float f; unsigned u; } x; x.f = v;
    unsigned r = x.u + 0x7fffu + ((x.u >> 16) & 1u);
    return (u16)(r >> 16);
}

__device__ __forceinline__ float bf2f(u16 v) {
    union { unsigned u; float f; } x; x.u = ((unsigned)v) << 16;
    return x.f;
}

// Fused prep: blocks 0..4095 = conv step + state shift + flag + bf16 casts;
// blocks 4096..6143 = weight f32->bf16 re-layout to wt2[mat][ks][e][k%32]
// (k-chunk-major so kfused's B-frag loads are contiguous 1KB per wave).
__global__ __launch_bounds__(256) void kprep(
    const float* __restrict__ inputs, const float* __restrict__ cs,
    const float* __restrict__ ck, const float* __restrict__ cb,
    const float* __restrict__ h, const float* __restrict__ n,
    const float* W0, const float* W1, const float* W2, const float* W3,
    const float* W4, const float* W5, const float* W6, const float* W7,
    float* __restrict__ ncs_out, u16* __restrict__ convact,
    u16* __restrict__ hbf, u16* __restrict__ inbf,
    u16* __restrict__ wt, int* __restrict__ flag) {
    __shared__ float tile[32][33];
    int bid = blockIdx.x;
    int t = threadIdx.x;
    if (bid < 4096) {
        int idx = bid * 256 + t;
        int flat = idx << 2;
        int b = flat >> 10;
        int f = flat & 1023;
        const f32x4 x  = *(const f32x4*)(inputs + flat);
        const f32x4 c1 = *(const f32x4*)(cs + b * 4096 + 1024 + f);
        const f32x4 c2 = *(const f32x4*)(cs + b * 4096 + 2048 + f);
        const f32x4 c3 = *(const f32x4*)(cs + b * 4096 + 3072 + f);
        const f32x4 k0 = *(const f32x4*)(ck + f);
        const f32x4 k1 = *(const f32x4*)(ck + 1024 + f);
        const f32x4 k2 = *(const f32x4*)(ck + 2048 + f);
        const f32x4 k3 = *(const f32x4*)(ck + 3072 + f);
        const f32x4 bias = *(const f32x4*)(cb + f);
        const f32x4 h4 = *(const f32x4*)(h + flat);
        const f32x4 nv = *(const f32x4*)(n + flat);

        // any(n != 0): benign race, only 1 ever stored (plain store per wave)
        bool any = (nv[0] != 0.f) || (nv[1] != 0.f) || (nv[2] != 0.f) || (nv[3] != 0.f);
        unsigned long long msk = __ballot(any);
        if (msk && (t & 63) == 0) *flag = 1;

        u16x4 ca, hb, ib;
        #pragma unroll
        for (int q = 0; q < 4; ++q) {
            float v = c1[q] * k0[q] + c2[q] * k1[q] + c3[q] * k2[q] + x[q] * k3[q] + bias[q];
            float a = v / (1.f + expf(-v));   // silu
            ca[q] = f2bf(a);
            hb[q] = f2bf(h4[q]);
            ib[q] = f2bf(x[q]);
        }
        *(u16x4*)(convact + flat) = ca;
        *(u16x4*)(hbf + flat) = hb;
        *(u16x4*)(inbf + flat) = ib;

        float* ob = ncs_out + b * 4096 + f;
        *(f32x4*)(ob)        = c1;
        *(f32x4*)(ob + 1024) = c2;
        *(f32x4*)(ob + 2048) = c3;
        *(f32x4*)(ob + 3072) = x;
    } else {
        int wb = bid - 4096;          // 0..2047 = 64 tiles x 4 heads x 8 mats
        int gx = wb & 63;
        int hd = (wb >> 6) & 3;
        int mat = wb >> 8;
        const float* tab[8] = {W0, W1, W2, W3, W4, W5, W6, W7};
        const float* src = tab[mat] + hd * 65536;
        u16* dst = wt + (mat * 4 + hd) * 65536;
        int tx = t & 31, ty = t >> 5;
        int bx = (gx & 7) * 32;   // e tile
        int by = (gx >> 3) * 32;  // k tile
        #pragma unroll
        for (int r = 0; r < 4; ++r)
            tile[ty + r * 8][tx] = src[(by + ty + r * 8) * 256 + bx + tx];
        __syncthreads();
        // wt2[ks = k/32][e][k%32]: e = bx+ty+r*8, k = by+tx
        #pragma unroll
        for (int r = 0; r < 4; ++r)
            dst[(by >> 5) * 8192 + (bx + ty + r * 8) * 32 + tx] = f2bf(tile[tx][ty + r * 8]);
    }
}

// Fused GEMM + pointwise + per-head LayerNorm.
// Block = 32 rows x one head x ALL 4 gates (cols = 4*256). 1024 threads,
// 16 waves = (gate g, quarter q), wave tile 32 rows x 64 cols, acc[2][4].
// A (convact/inputs/hbf row-slices, 48 KB) staged ONCE in swizzled LDS ->
// K-loop has NO barriers; B-frags streamed from L2 via coalesced 1KB loads
// (wt2 layout). Epilogue: acc -> 64 KB LDS gbuf (bf16) -> pointwise + LN
// (32-lane shuffle) -> direct output writes. gates16 round-trip eliminated.
// grid: x = 128 mtiles, y = 4 heads.
__global__ __launch_bounds__(1024, 4) void kfused(
    const u16* __restrict__ convact, const u16* __restrict__ inbf,
    const u16* __restrict__ hbf, const u16* __restrict__ wt2,
    const float* __restrict__ bgi, const float* __restrict__ bgf,
    const float* __restrict__ bgz, const float* __restrict__ bgo,
    const float* __restrict__ c, const float* __restrict__ n,
    const float* __restrict__ m, const float* __restrict__ ln_scale,
    const int* __restrict__ flagp, float* __restrict__ out) {
    // A: 3 x 16 KB (rows 32 x 32 granules of 16B, granule g at slot g^(row&7));
    // epilogue reuses all 64 KB as gbuf[32][1024] bf16.
    __shared__ __align__(16) u16 smem[32768];

    int t = threadIdx.x;
    int mtile = blockIdx.x;
    int hd = blockIdx.y;
    int row0 = mtile * 32;

    // ---- one-time A staging (3072 x 16B granule loads, pre-swizzled source)
    {
        int r = t >> 5, gd = t & 31;
        int gl = gd ^ (r & 7);
        size_t soff = (size_t)(row0 + r) * 1024 + hd * 256 + gl * 8;
        __builtin_amdgcn_global_load_lds(
            (const __attribute__((address_space(1))) void*)(convact + soff),
            (__attribute__((address_space(3))) void*)(&smem[t * 8]), 16, 0, 0);
        __builtin_amdgcn_global_load_lds(
            (const __attribute__((address_space(1))) void*)(inbf + soff),
            (__attribute__((address_space(3))) void*)(&smem[8192 + t * 8]), 16, 0, 0);
        __builtin_amdgcn_global_load_lds(
            (const __attribute__((address_space(1))) void*)(hbf + soff),
            (__attribute__((address_space(3))) void*)(&smem[16384 + t * 8]), 16, 0, 0);
    }
    __syncthreads();

    int lane = t & 63, lr = lane & 15, lk = lane >> 4;
    int w = t >> 6;
    int g = w >> 2;        // gate
    int q = w & 3;         // column quarter (64 cols)

    f32x4 acc[2][4];
    #pragma unroll
    for (int i = 0; i < 2; ++i)
        #pragma unroll
        for (int j = 0; j < 4; ++j)
            acc[i][j] = (f32x4){0.f, 0.f, 0.f, 0.f};

    const u16* bW = wt2 + (size_t)(g * 4 + hd) * 65536;
    const u16* bR = wt2 + (size_t)((g + 4) * 4 + hd) * 65536;
    int bcol = (q * 64 + lr) * 32 + lk * 8;
    int aselW = (g < 2) ? 0 : 8192;     // i,f <- convact ; z,o <- inputs
    int grs = (lr & 7);                 // row&7 is same for row=lr and row=16+lr

    // K first half: x-side (W matrices), A from convact/inputs
    #pragma unroll 4
    for (int ks = 0; ks < 8; ++ks) {
        bf16x8 b0 = *(const bf16x8*)(bW + ks * 8192 + bcol);
        bf16x8 b1 = *(const bf16x8*)(bW + ks * 8192 + bcol + 512);
        bf16x8 b2 = *(const bf16x8*)(bW + ks * 8192 + bcol + 1024);
        bf16x8 b3 = *(const bf16x8*)(bW + ks * 8192 + bcol + 1536);
        int gr = (ks * 4 + lk) ^ grs;
        bf16x8 a0 = *(const bf16x8*)&smem[aselW + lr * 256 + gr * 8];
        bf16x8 a1 = *(const bf16x8*)&smem[aselW + (16 + lr) * 256 + gr * 8];
        acc[0][0] = __builtin_amdgcn_mfma_f32_16x16x32_bf16(a0, b0, acc[0][0], 0, 0, 0);
        acc[0][1] = __builtin_amdgcn_mfma_f32_16x16x32_bf16(a0, b1, acc[0][1], 0, 0, 0);
        acc[0][2] = __builtin_amdgcn_mfma_f32_16x16x32_bf16(a0, b2, acc[0][2], 0, 0, 0);
        acc[0][3] = __builtin_amdgcn_mfma_f32_16x16x32_bf16(a0, b3, acc[0][3], 0, 0, 0);
        acc[1][0] = __builtin_amdgcn_mfma_f32_16x16x32_bf16(a1, b0, acc[1][0], 0, 0, 0);
        acc[1][1] = __builtin_amdgcn_mfma_f32_16x16x32_bf16(a1, b1, acc[1][1], 0, 0, 0);
        acc[1][2] = __builtin_amdgcn_mfma_f32_16x16x32_bf16(a1, b2, acc[1][2], 0, 0, 0);
        acc[1][3] = __builtin_amdgcn_mfma_f32_16x16x32_bf16(a1, b3, acc[1][3], 0, 0, 0);
    }
    // K second half: h-side (R matrices), A from hbf
    #pragma unroll 4
    for (int ks = 0; ks < 8; ++ks) {
        bf16x8 b0 = *(const bf16x8*)(bR + ks * 8192 + bcol);
        bf16x8 b1 = *(const bf16x8*)(bR + ks * 8192 + bcol + 512);
        bf16x8 b2 = *(const bf16x8*)(bR + ks * 8192 + bcol + 1024);
        bf16x8 b3 = *(const bf16x8*)(bR + ks * 8192 + bcol + 1536);
        int gr = (ks * 4 + lk) ^ grs;
        bf16x8 a0 = *(const bf16x8*)&smem[16384 + lr * 256 + gr * 8];
        bf16x8 a1 = *(const bf16x8*)&smem[16384 + (16 + lr) * 256 + gr * 8];
        acc[0][0] = __builtin_amdgcn_mfma_f32_16x16x32_bf16(a0, b0, acc[0][0], 0, 0, 0);
        acc[0][1] = __builtin_amdgcn_mfma_f32_16x16x32_bf16(a0, b1, acc[0][1], 0, 0, 0);
        acc[0][2] = __builtin_amdgcn_mfma_f32_16x16x32_bf16(a0, b2, acc[0][2], 0, 0, 0);
        acc[0][3] = __builtin_amdgcn_mfma_f32_16x16x32_bf16(a0, b3, acc[0][3], 0, 0, 0);
        acc[1][0] = __builtin_amdgcn_mfma_f32_16x16x32_bf16(a1, b0, acc[1][0], 0, 0, 0);
        acc[1][1] = __builtin_amdgcn_mfma_f32_16x16x32_bf16(a1, b1, acc[1][1], 0, 0, 0);
        acc[1][2] = __builtin_amdgcn_mfma_f32_16x16x32_bf16(a1, b2, acc[1][2], 0, 0, 0);
        acc[1][3] = __builtin_amdgcn_mfma_f32_16x16x32_bf16(a1, b3, acc[1][3], 0, 0, 0);
    }

    // ---- epilogue: acc (+bias) -> gbuf[32][1024] bf16 (reuses A region)
    __syncthreads();   // all A reads complete before overwrite
    {
        const float* bt = (g == 0 ? bgi : g == 1 ? bgf : g == 2 ? bgz : bgo)
                          + hd * 256 + q * 64;
        #pragma unroll
        for (int nt = 0; nt < 4; ++nt) {
            float bv = bt[nt * 16 + lr];
            int col = g * 256 + q * 64 + nt * 16 + lr;
            #pragma unroll
            for (int mt = 0; mt < 2; ++mt)
                #pragma unroll
                for (int r = 0; r < 4; ++r)
                    smem[(mt * 16 + lk * 4 + r) * 1024 + col] = f2bf(acc[mt][nt][r] + bv);
        }
    }
    __syncthreads();

    // ---- pointwise + LN: thread -> (row = t>>5, 8 elems at e0 = (t&31)*8)
    {
        int prow = t >> 5;
        int e0 = (t & 31) * 8;
        u16x8 iv = *(const u16x8*)&smem[prow * 1024 + e0];
        u16x8 fv = *(const u16x8*)&smem[prow * 1024 + 256 + e0];
        u16x8 zv = *(const u16x8*)&smem[prow * 1024 + 512 + e0];
        u16x8 ov = *(const u16x8*)&smem[prow * 1024 + 768 + e0];
        size_t idx = (size_t)(row0 + prow) * 1024 + hd * 256 + e0;
        f32x4 cv0 = *(const f32x4*)(c + idx), cv1 = *(const f32x4*)(c + idx + 4);
        f32x4 nv0 = *(const f32x4*)(n + idx), nv1 = *(const f32x4*)(n + idx + 4);
        f32x4 mv0 = *(const f32x4*)(m + idx), mv1 = *(const f32x4*)(m + idx + 4);
        f32x4 sc0 = *(const f32x4*)(ln_scale + hd * 256 + e0);
        f32x4 sc1 = *(const f32x4*)(ln_scale + hd * 256 + e0 + 4);
        int flag = *flagp;

        float cn[8], nn[8], mn[8], hn[8];
        float s = 0.f, ss = 0.f;
        #pragma unroll
        for (int e = 0; e < 8; ++e) {
            float I = bf2f(iv[e]);
            float Fg = bf2f(fv[e]);
            float Z = bf2f(zv[e]);
            float O = bf2f(ov[e]);
            float cvq = (e < 4) ? cv0[e] : cv1[e - 4];
            float nvq = (e < 4) ? nv0[e] : nv1[e - 4];
            float mvq = (e < 4) ? mv0[e] : mv1[e - 4];
            float og = 1.f / (1.f + expf(-O));
            float lf = (Fg >= 0.f) ? -log1pf(expf(-Fg)) : (Fg - log1pf(expf(Fg)));
            float mnew = flag ? fmaxf(lf + mvq, I) : I;
            float ip = fminf(expf(I - mnew), 1.f);
            float fp = fminf(expf(lf + mvq - mnew), 1.f);
            float cnew = fp * cvq + ip * tanhf(Z);
            float nnew = fp * nvq + ip;
            float hnew = og * (cnew / fmaxf(nnew, 1e-6f));
            cn[e] = cnew; nn[e] = nnew; mn[e] = mnew; hn[e] = hnew;
            s += hnew; ss += hnew * hnew;
        }
        // LN reduce across the 32 lanes of this row (lanes grouped in half-wave)
        #pragma unroll
        for (int off = 16; off >= 1; off >>= 1) {
            s  += __shfl_xor(s, off);
            ss += __shfl_xor(ss, off);
        }
        float mu = s * (1.f / 256.f);
        float var = ss * (1.f / 256.f) - mu * mu;
        float rs = rsqrtf(var + 1e-6f);

        f32x4 o0, o1, c0, c1, n0, n1, m0, m1, h0, h1;
        #pragma unroll
        for (int e = 0; e < 4; ++e) {
            o0[e] = (hn[e] - mu) * rs * sc0[e];
            o1[e] = (hn[e + 4] - mu) * rs * sc1[e];
            c0[e] = cn[e]; c1[e] = cn[e + 4];
            n0[e] = nn[e]; n1[e] = nn[e + 4];
            m0[e] = mn[e]; m1[e] = mn[e + 4];
            h0[e] = hn[e]; h1[e] = hn[e + 4];
        }
        *(f32x4*)(out + idx) = o0;
        *(f32x4*)(out + idx + 4) = o1;
        *(f32x4*)(out + (size_t)BF_ELEMS + idx) = c0;
        *(f32x4*)(out + (size_t)BF_ELEMS + idx + 4) = c1;
        *(f32x4*)(out + 2 * (size_t)BF_ELEMS + idx) = n0;
        *(f32x4*)(out + 2 * (size_t)BF_ELEMS + idx + 4) = n1;
        *(f32x4*)(out + 3 * (size_t)BF_ELEMS + idx) = m0;
        *(f32x4*)(out + 3 * (size_t)BF_ELEMS + idx + 4) = m1;
        *(f32x4*)(out + 4 * (size_t)BF_ELEMS + idx) = h0;
        *(f32x4*)(out + 4 * (size_t)BF_ELEMS + idx + 4) = h1;
    }
}

extern "C" void kernel_launch(void* const* d_in, const int* in_sizes, int n_in,
                              void* d_out, int out_size, void* d_ws, size_t ws_size,
                              hipStream_t stream) {
    const float* inputs = (const float*)d_in[0];
    const float* c = (const float*)d_in[1];
    const float* n = (const float*)d_in[2];
    const float* m = (const float*)d_in[3];
    const float* h = (const float*)d_in[4];
    const float* conv_state = (const float*)d_in[5];
    const float* conv_kernel = (const float*)d_in[6];
    const float* conv_bias = (const float*)d_in[7];
    const float* W[8];
    for (int i = 0; i < 8; ++i) W[i] = (const float*)d_in[8 + i];
    const float* bgi = (const float*)d_in[16];
    const float* bgf = (const float*)d_in[17];
    const float* bgz = (const float*)d_in[18];
    const float* bgo = (const float*)d_in[19];
    const float* ln_scale = (const float*)d_in[20];
    float* out = (float*)d_out;

    char* ws = (char*)d_ws;
    int* flag = (int*)ws;
    u16* convact = (u16*)(ws + 256);
    u16* hbf = convact + BF_ELEMS;
    u16* inbf = hbf + BF_ELEMS;
    u16* wt2 = inbf + BF_ELEMS;                      // 8*4*65536 bf16

    hipMemsetAsync(flag, 0, 4, stream);
    kprep<<<6144, 256, 0, stream>>>(inputs, conv_state, conv_kernel, conv_bias, h, n,
                                    W[0], W[1], W[2], W[3], W[4], W[5], W[6], W[7],
                                    out + 5 * (size_t)BF_ELEMS, convact, hbf, inbf, wt2, flag);
    kfused<<<dim3(128, 4), 1024, 0, stream>>>(convact, inbf, hbf, wt2,
                                              bgi, bgf, bgz, bgo,
                                              c, n, m, ln_scale, flag, out);
}